// Round 12
// baseline (2254.886 us; speedup 1.0000x reference)
//
#include <hip/hip_runtime.h>
#include <type_traits>
#include <utility>
#include <cstdint>

typedef unsigned short u16;
typedef __attribute__((ext_vector_type(4))) float f32x4;
typedef __attribute__((ext_vector_type(8))) short s16x8;
typedef __attribute__((ext_vector_type(8))) __bf16 b16x8;

// ---- MFMA operand-type hedge: builtin takes either short8 or __bf16x8 ----
template <typename T, typename = void> struct MfmaTakes : std::false_type {};
template <typename T>
struct MfmaTakes<T, std::void_t<decltype(__builtin_amdgcn_mfma_f32_16x16x32_bf16(
    std::declval<T>(), std::declval<T>(), std::declval<f32x4>(), 0, 0, 0))>>
    : std::true_type {};
using abvec = std::conditional_t<MfmaTakes<s16x8>::value, s16x8, b16x8>;
static_assert(sizeof(abvec) == 16, "frag must be 4 VGPRs");

template <typename T>
__device__ __forceinline__ f32x4 mfma_bf16(T a, T b, f32x4 c) {
  return __builtin_amdgcn_mfma_f32_16x16x32_bf16(a, b, c, 0, 0, 0);
}

__device__ __forceinline__ float b2f(u16 v) {
  union { unsigned u; float f; } x; x.u = ((unsigned)v) << 16; return x.f;
}
__device__ __forceinline__ u16 f2b(float f) {
  union { float f; unsigned u; } x; x.f = f;
  unsigned r = x.u + 0x7fffu + ((x.u >> 16) & 1u);
  return (u16)(r >> 16);
}

__device__ __forceinline__ void gld16(const void* g, void* l) {
  auto gp = reinterpret_cast<const __attribute__((address_space(1))) unsigned int*>(
      reinterpret_cast<uintptr_t>(g));
  auto lp = reinterpret_cast<__attribute__((address_space(3))) unsigned int*>(
      reinterpret_cast<uintptr_t>(l));
  __builtin_amdgcn_global_load_lds(gp, lp, 16, 0, 0);
}

#define NN 16384
#define NE 131072
#define NG 16

// ---------------- dtype detect: bf16 vs f32 input buffers ----------------
__global__ void detect_dtype(const u16* __restrict__ x, int* __restrict__ flag) {
  __shared__ int cnt;
  if (threadIdx.x == 0) cnt = 0;
  __syncthreads();
  int local = 0;
#pragma unroll
  for (int i = 0; i < 8; i++) {
    u16 h = x[threadIdx.x * 8 + i];
    int e = (h >> 7) & 0xFF;
    if (h == 0 || (e >= 110 && e <= 134)) local++;
  }
  atomicAdd(&cnt, local);
  __syncthreads();
  if (threadIdx.x == 0) *flag = (cnt >= 1700) ? 1 : 0;
}

// ---------------- batched convert of tensors to bf16 ----------------
struct CvtJob {
  const void* src[14];
  void* dst[14];
  int n[14];
};

__global__ __launch_bounds__(256) void cvt_all(CvtJob jb, const int* __restrict__ flag) {
  const int idx = blockIdx.x * 256 + threadIdx.x;
  const int f = *flag;
  int off = 0;
#pragma unroll
  for (int j = 0; j < 14; j++) {
    const int nn = jb.n[j];
    if (idx < off + nn) {
      const int i = idx - off;
      u16 v = f ? ((const u16*)jb.src[j])[i]
                : f2b(((const float*)jb.src[j])[i]);
      ((u16*)jb.dst[j])[i] = v;
      return;
    }
    off += nn;
  }
}

// ---------------- GEMM: C[M,N](ldc) = act(A[M,K] @ Bt[N,K]^T + bias) ----------------
// BK=64 + XOR k-slot swizzle (round 10/11 wins). Epilogue: wave-private 8KB LDS
// staging (one barrier total, no inter-wave serialization), col8^row XOR layout,
// ds_read_b128 + 16B coalesced stores covering full 128B row segments.
__global__ __launch_bounds__(256) void gemm_bt(
    const u16* __restrict__ A, const u16* __restrict__ Bt,
    const u16* __restrict__ bias, u16* __restrict__ C,
    int M, int N, int K, int ldc, int relu)
{
  __shared__ alignas(16) u16 smem[16384];  // 32KB: As0,As1,Bs0,Bs1 (4096 u16 each)
  u16* As0 = smem;
  u16* As1 = smem + 4096;
  u16* Bs0 = smem + 8192;
  u16* Bs1 = smem + 12288;
  const int tid = threadIdx.x;
  const int wave = tid >> 6, lane = tid & 63;
  const int m0 = blockIdx.x * 128, n0 = blockIdx.y * 128;

  const int srow = lane >> 2;              // 0..15
  const int kslot = lane & 3;              // 16B slot within row's 64B
  const int sswz = (srow >> 1) & 3;        // row-based XOR swizzle
  const u16* gA = A + (size_t)(m0 + wave * 32 + srow) * K + (kslot ^ sswz) * 8;
  const u16* gB = Bt + (size_t)(n0 + wave * 32 + srow) * K + (kslot ^ sswz) * 8;
  const int loff = (wave * 32 + srow) * 32 + kslot * 8;  // == wave*2048B + lane*16B

  const int wm = (wave >> 1) * 64;
  const int wn = (wave & 1) * 64;
  const int fr = lane & 15;
  const int fks = ((lane >> 4) ^ ((fr >> 1) & 3)) * 8;   // swizzled read slot

  f32x4 acc[4][4] = {};

  int k0 = 0;
  for (; k0 + 64 <= K; k0 += 64) {
    __syncthreads();
    gld16(gA,      As0 + loff); gld16(gA + 16 * (size_t)K,      As0 + loff + 512);
    gld16(gA + 32, As1 + loff); gld16(gA + 16 * (size_t)K + 32, As1 + loff + 512);
    gld16(gB,      Bs0 + loff); gld16(gB + 16 * (size_t)K,      Bs0 + loff + 512);
    gld16(gB + 32, Bs1 + loff); gld16(gB + 16 * (size_t)K + 32, Bs1 + loff + 512);
    gA += 64; gB += 64;
    __syncthreads();

    abvec af[4], bf[4];
#pragma unroll
    for (int i = 0; i < 4; i++)
      af[i] = *(const abvec*)&As0[(wm + i * 16 + fr) * 32 + fks];
#pragma unroll
    for (int i = 0; i < 4; i++)
      bf[i] = *(const abvec*)&Bs0[(wn + i * 16 + fr) * 32 + fks];
#pragma unroll
    for (int mi = 0; mi < 4; mi++)
#pragma unroll
      for (int ni = 0; ni < 4; ni++)
        acc[mi][ni] = mfma_bf16(af[mi], bf[ni], acc[mi][ni]);

#pragma unroll
    for (int i = 0; i < 4; i++)
      af[i] = *(const abvec*)&As1[(wm + i * 16 + fr) * 32 + fks];
#pragma unroll
    for (int i = 0; i < 4; i++)
      bf[i] = *(const abvec*)&Bs1[(wn + i * 16 + fr) * 32 + fks];
#pragma unroll
    for (int mi = 0; mi < 4; mi++)
#pragma unroll
      for (int ni = 0; ni < 4; ni++)
        acc[mi][ni] = mfma_bf16(af[mi], bf[ni], acc[mi][ni]);
  }
  if (k0 < K) {                            // 32-k tail (K % 64 == 32)
    __syncthreads();
    gld16(gA, As0 + loff); gld16(gA + 16 * (size_t)K, As0 + loff + 512);
    gld16(gB, Bs0 + loff); gld16(gB + 16 * (size_t)K, Bs0 + loff + 512);
    __syncthreads();

    abvec af[4], bf[4];
#pragma unroll
    for (int i = 0; i < 4; i++)
      af[i] = *(const abvec*)&As0[(wm + i * 16 + fr) * 32 + fks];
#pragma unroll
    for (int i = 0; i < 4; i++)
      bf[i] = *(const abvec*)&Bs0[(wn + i * 16 + fr) * 32 + fks];
#pragma unroll
    for (int mi = 0; mi < 4; mi++)
#pragma unroll
      for (int ni = 0; ni < 4; ni++)
        acc[mi][ni] = mfma_bf16(af[mi], bf[ni], acc[mi][ni]);
  }

  // ---- epilogue: wave-private LDS staging (one barrier, no inter-wave serial) ----
  const int crow0 = (lane >> 4) * 4;
  float bv[4];
#pragma unroll
  for (int ni = 0; ni < 4; ni++) bv[ni] = b2f(bias[n0 + wn + ni * 16 + fr]);

  __syncthreads();                         // all waves done reading As/Bs
  u16* W = smem + wave * 4096;             // private 64x64, col8 ^ (row&7) swizzle
#pragma unroll
  for (int mi = 0; mi < 4; mi++) {
#pragma unroll
    for (int ni = 0; ni < 4; ni++) {
      f32x4 v = acc[mi][ni];
      const int colx = ni * 16 + fr;
      const int cl = colx & 7, ch = colx >> 3;
#pragma unroll
      for (int r = 0; r < 4; r++) {
        const int rowx = mi * 16 + crow0 + r;
        float f = v[r] + bv[ni];
        if (relu) f = fmaxf(f, 0.0f);
        W[rowx * 64 + ((ch ^ (rowx & 7)) << 3) + cl] = f2b(f);
      }
    }
  }
  __asm__ volatile("s_waitcnt lgkmcnt(0)" ::: "memory");
#pragma unroll
  for (int p = 0; p < 8; p++) {
    const int rowx = p * 8 + (lane >> 3);
    const int pc = lane & 7;
    const int lc = pc ^ (rowx & 7);
    s16x8 val = *(const s16x8*)&W[rowx * 64 + pc * 8];
    *(s16x8*)&C[(size_t)(m0 + wm + rowx) * ldc + n0 + wn + lc * 8] = val;
  }
}

// -------- transpose + zero-pad + convert + optional K-permute --------
__global__ __launch_bounds__(256) void transpose_pad(
    const void* __restrict__ src, u16* __restrict__ dst, int K, int N, int Kp,
    int perm, const int* __restrict__ flag)
{
  __shared__ u16 tile[32][33];
  const int f = *flag;
  const u16* s16p = (const u16*)src;
  const float* sfp = (const float*)src;
  const int kb = blockIdx.x * 32, nb = blockIdx.y * 32;
  const int tx = threadIdx.x & 31, ty = threadIdx.x >> 5;
#pragma unroll
  for (int i = 0; i < 32; i += 8) {
    int k = kb + ty + i, n = nb + tx;
    u16 v = 0;
    if (k < K && n < N)
      v = f ? s16p[(size_t)k * N + n] : f2b(sfp[(size_t)k * N + n]);
    tile[ty + i][tx] = v;
  }
  __syncthreads();
#pragma unroll
  for (int i = 0; i < 32; i += 8) {
    int n = nb + ty + i, k = kb + tx;
    if (n < N && k < Kp) {
      int nk = perm ? (k < 9 ? 512 + k : (k < 521 ? k - 9 : k)) : k;
      dst[(size_t)n * Kp + nk] = tile[tx][ty + i];
    }
  }
}

// -------- dim_reduce K-split: grid (16 graphs, 8 k-tiles), partials into f32 --------
__global__ __launch_bounds__(256) void dim_reduce2(
    const u16* __restrict__ u, const void* __restrict__ w,
    float* __restrict__ uacc, const int* __restrict__ flag)
{
  const int g = blockIdx.x, kt = blockIdx.y, j = threadIdx.x;
  const int f = *flag;
  __shared__ u16 us[512];
  us[j] = u[g * 4096 + kt * 512 + j];
  us[256 + j] = u[g * 4096 + kt * 512 + 256 + j];
  __syncthreads();
  float acc = 0.0f;
  if (f) {
    const u16* wp = (const u16*)w + (size_t)(kt * 512) * 256 + j;
#pragma unroll 8
    for (int k = 0; k < 512; k++) acc += b2f(us[k]) * b2f(wp[(size_t)k * 256]);
  } else {
    const float* wp = (const float*)w + (size_t)(kt * 512) * 256 + j;
#pragma unroll 8
    for (int k = 0; k < 512; k++) acc += b2f(us[k]) * wp[(size_t)k * 256];
  }
  atomicAdd(&uacc[g * 256 + j], acc);
}

__global__ __launch_bounds__(256) void finish_ur(
    const float* __restrict__ uacc, const u16* __restrict__ bdr,
    u16* __restrict__ ur)
{
  const int i = blockIdx.x * 256 + threadIdx.x;  // 4096
  ur[i] = f2b(uacc[i] + b2f(bdr[i & 255]));
}

// -------- edge sort by row: count -> prefix -> perm --------
__global__ __launch_bounds__(256) void count_edges(
    const int* __restrict__ row, int* __restrict__ cnt)
{
  const int e = blockIdx.x * 256 + threadIdx.x;
  if (e < NE) atomicAdd(&cnt[row[e]], 1);
}

__global__ __launch_bounds__(256) void prefix_offs(
    const int* __restrict__ cnt, int* __restrict__ offs, int* __restrict__ cursor)
{
  __shared__ int part[256];
  __shared__ int base[256];
  const int t = threadIdx.x;
  int s = 0;
#pragma unroll
  for (int i = 0; i < 64; i++) s += cnt[t * 64 + i];
  part[t] = s;
  __syncthreads();
  if (t == 0) {
    int r = 0;
    for (int i = 0; i < 256; i++) { base[i] = r; r += part[i]; }
  }
  __syncthreads();
  int r = base[t];
#pragma unroll
  for (int i = 0; i < 64; i++) {
    const int n = t * 64 + i;
    offs[n] = r; cursor[n] = r; r += cnt[n];
  }
  if (t == 255) offs[16384] = r;   // == NE
}

__global__ __launch_bounds__(256) void build_perm(
    const int* __restrict__ row, int* __restrict__ cursor, int* __restrict__ eperm)
{
  const int e = blockIdx.x * 256 + threadIdx.x;
  const int pos = atomicAdd(&cursor[row[e]], 1);
  eperm[pos] = e;
}

// -------- edge input gather (sorted order) --------
__global__ __launch_bounds__(256) void build_ein(
    const u16* __restrict__ x, const u16* __restrict__ ea,
    const u16* __restrict__ ur, const int* __restrict__ row,
    const int* __restrict__ col, const int* __restrict__ batch,
    const int* __restrict__ eperm, u16* __restrict__ out, int e0)
{
  const int idx = blockIdx.x * 256 + threadIdx.x;   // echunk*36
  const int le = idx / 36, g = idx % 36;
  const int c0 = g * 8;
  const int e = eperm[e0 + le];
  const int r = row[e];
  alignas(16) u16 v[8];
  if (c0 >= 24 && c0 + 8 <= 275) {
    const u16* up = &ur[batch[r] * 256 + (c0 - 19)];
#pragma unroll
    for (int j = 0; j < 8; j++) v[j] = up[j];
  } else {
    const int cl = col[e];
    const int b = batch[r];
#pragma unroll
    for (int j = 0; j < 8; j++) {
      const int c = c0 + j;
      u16 t;
      if (c < 9)        t = x[r * 9 + c];
      else if (c < 18)  t = x[cl * 9 + (c - 9)];
      else if (c == 18) t = ea[e];
      else if (c < 275) t = ur[b * 256 + (c - 19)];
      else              t = 0;
      v[j] = t;
    }
  }
  *(s16x8*)&out[(size_t)le * 288 + c0] = *(const s16x8*)v;
}

// -------- fill nin1 cols 512..543 (sorted order) --------
__global__ __launch_bounds__(256) void fill_nin1_tail(
    const u16* __restrict__ x, const int* __restrict__ col,
    const int* __restrict__ eperm, u16* __restrict__ out, int e0)
{
  const int idx = blockIdx.x * 256 + threadIdx.x;   // echunk*4
  const int le = idx >> 2, j8 = idx & 3;
  const int c0 = 512 + j8 * 8;
  const int cl = col[eperm[e0 + le]];
  alignas(16) u16 v[8];
#pragma unroll
  for (int j = 0; j < 8; j++) {
    const int c = c0 + j;
    v[j] = (c < 521) ? x[cl * 9 + (c - 512)] : (u16)0;
  }
  *(s16x8*)&out[(size_t)le * 544 + c0] = *(const s16x8*)v;
}

// -------- segment reduce (sorted rows, no atomics; chunks stream-serialized) --------
__global__ __launch_bounds__(256) void seg_reduce(
    const u16* __restrict__ h, const int* __restrict__ offs,
    float* __restrict__ agg, int e0, int echunk)
{
  const int wave = threadIdx.x >> 6, lane = threadIdx.x & 63;
  const int n = blockIdx.x * 4 + wave;
  int lo = offs[n], hi = offs[n + 1];
  lo = lo > e0 ? lo : e0;
  const int e1 = e0 + echunk;
  hi = hi < e1 ? hi : e1;
  if (lo >= hi) return;
  const int c0 = lane * 8;
  float acc[8] = {};
  for (int i = lo; i < hi; i++) {
    s16x8 v = *(const s16x8*)&h[(size_t)(i - e0) * 512 + c0];
#pragma unroll
    for (int j = 0; j < 8; j++) acc[j] += b2f((u16)v[j]);
  }
  float* ap = &agg[(size_t)n * 512 + c0];
#pragma unroll
  for (int j = 0; j < 8; j++) ap[j] += acc[j];
}

// -------- nin2 build (permuted): [agg/cnt(512) | x(9) | ur(256) | pad(23)] --------
__global__ __launch_bounds__(256) void build_nin2(
    const u16* __restrict__ x, const float* __restrict__ agg,
    const int* __restrict__ cnt, const u16* __restrict__ ur,
    const int* __restrict__ batch, u16* __restrict__ out, int n0)
{
  const int idx = blockIdx.x * 256 + threadIdx.x;   // nodch*100
  const int le = idx / 100, g = idx % 100;
  const int c0 = g * 8;
  const int n = n0 + le;
  alignas(16) u16 v[8];
  if (c0 < 512) {
    const float den = fmaxf((float)cnt[n], 1.0f);
    const f32x4* ap = (const f32x4*)&agg[(size_t)n * 512 + c0];
    f32x4 a0 = ap[0], a1 = ap[1];
#pragma unroll
    for (int j = 0; j < 4; j++) { v[j] = f2b(a0[j] / den); v[4 + j] = f2b(a1[j] / den); }
  } else {
    const int b = batch[n];
#pragma unroll
    for (int j = 0; j < 8; j++) {
      const int c = c0 + j;
      u16 t;
      if (c < 521)      t = x[n * 9 + (c - 512)];
      else if (c < 777) t = ur[b * 256 + (c - 521)];
      else              t = 0;
      v[j] = t;
    }
  }
  *(s16x8*)&out[(size_t)le * 800 + c0] = *(const s16x8*)v;
}

// -------- final: out[n0+n] = h[n,:] . w + b --------
__global__ __launch_bounds__(256) void final_dot(
    const u16* __restrict__ h, const u16* __restrict__ w,
    const u16* __restrict__ b, void* __restrict__ out, int n0,
    const int* __restrict__ flag)
{
  const int wave = threadIdx.x >> 6, lane = threadIdx.x & 63;
  const int n = blockIdx.x * 4 + wave;
  const u16* hp = h + (size_t)n * 512 + lane * 8;
  const u16* wp = w + lane * 8;
  float s = 0.0f;
#pragma unroll
  for (int i = 0; i < 8; i++) s += b2f(hp[i]) * b2f(wp[i]);
#pragma unroll
  for (int off = 32; off > 0; off >>= 1) s += __shfl_down(s, off, 64);
  if (lane == 0) {
    float r = s + b2f(b[0]);
    if (*flag) ((u16*)out)[n0 + n] = f2b(r);
    else       ((float*)out)[n0 + n] = r;
  }
}

// ---------------- workspace layout (static part) ----------------
constexpr size_t OFF_FLAG = 0;
constexpr size_t OFF_XC   = 64;
constexpr size_t OFF_EAC  = OFF_XC   + 147456ull * 2;
constexpr size_t OFF_UC   = OFF_EAC  + 131072ull * 2;
constexpr size_t OFF_BDR  = OFF_UC   + 65536ull * 2;
constexpr size_t OFF_EB0  = OFF_BDR  + 256ull * 2;
constexpr size_t OFF_EB1  = OFF_EB0  + 1024ull * 2;
constexpr size_t OFF_EB2  = OFF_EB1  + 1024ull * 2;
constexpr size_t OFF_EB3  = OFF_EB2  + 1024ull * 2;
constexpr size_t OFF_EBF  = OFF_EB3  + 1024ull * 2;
constexpr size_t OFF_N1B0 = OFF_EBF  + 512ull * 2;
constexpr size_t OFF_N1B1 = OFF_N1B0 + 512ull * 2;
constexpr size_t OFF_N2B0 = OFF_N1B1 + 512ull * 2;
constexpr size_t OFF_N2W1 = OFF_N2B0 + 512ull * 2;
constexpr size_t OFF_N2B1 = OFF_N2W1 + 512ull * 2;
constexpr size_t OFF_OFFS = (OFF_N2B1 + 64 + 63) & ~63ull;     // 16385 int
constexpr size_t OFF_CUR  = OFF_OFFS + 16388ull * 4;           // 16384 int
constexpr size_t OFF_UACC = OFF_CUR  + 16384ull * 4;           // 4096 f32
static_assert(OFF_UACC + 4096 * 4 < (1ull << 20), "params+small fit in 1MB");

constexpr size_t OFF_W0T  = 1ull << 20;
constexpr size_t OFF_W1T  = OFF_W0T  + 1024ull * 288 * 2;
constexpr size_t OFF_W2T  = OFF_W1T  + 1024ull * 1024 * 2;
constexpr size_t OFF_W3T  = OFF_W2T  + 1024ull * 1024 * 2;
constexpr size_t OFF_WFT  = OFF_W3T  + 1024ull * 1024 * 2;
constexpr size_t OFF_N1W0 = OFF_WFT  + 512ull * 1024 * 2;
constexpr size_t OFF_N1W1 = OFF_N1W0 + 512ull * 544 * 2;
constexpr size_t OFF_N2W0 = OFF_N1W1 + 512ull * 512 * 2;
constexpr size_t OFF_UR   = OFF_N2W0 + 512ull * 800 * 2;
constexpr size_t OFF_CNT  = OFF_UR   + 16ull * 256 * 2;
constexpr size_t OFF_AGG  = OFF_CNT  + 16384ull * 4;
constexpr size_t OFF_BUF0 = OFF_AGG  + 16384ull * 512 * 4;   // dynamic from here (~42.5 MB)

extern "C" void kernel_launch(void* const* d_in, const int* in_sizes, int n_in,
                              void* d_out, int out_size, void* d_ws, size_t ws_size,
                              hipStream_t stream) {
  const void* x_r  = d_in[0];
  const void* ea_r = d_in[1];
  const void* u_r  = d_in[2];
  const int*  ei    = (const int*)d_in[3];
  const int*  batch = (const int*)d_in[4];
  const void* w_dr = d_in[5];
  const void* b_dr = d_in[6];
  const void* e_w0 = d_in[7];  const void* e_b0 = d_in[8];
  const void* e_w1 = d_in[9];  const void* e_b1 = d_in[10];
  const void* e_w2 = d_in[11]; const void* e_b2 = d_in[12];
  const void* e_w3 = d_in[13]; const void* e_b3 = d_in[14];
  const void* e_wf = d_in[15]; const void* e_bf = d_in[16];
  const void* n1w0 = d_in[17]; const void* n1b0 = d_in[18];
  const void* n1w1 = d_in[19]; const void* n1b1 = d_in[20];
  const void* n2w0 = d_in[21]; const void* n2b0 = d_in[22];
  const void* n2w1 = d_in[23]; const void* n2b1 = d_in[24];

  const int* row = ei;
  const int* col = ei + NE;

  char* ws = (char*)d_ws;
  int*   FLAG = (int*)(ws + OFF_FLAG);
  u16*   XC   = (u16*)(ws + OFF_XC);
  u16*   EAC  = (u16*)(ws + OFF_EAC);
  u16*   UC   = (u16*)(ws + OFF_UC);
  u16*   BDRC = (u16*)(ws + OFF_BDR);
  u16*   EB0C = (u16*)(ws + OFF_EB0);
  u16*   EB1C = (u16*)(ws + OFF_EB1);
  u16*   EB2C = (u16*)(ws + OFF_EB2);
  u16*   EB3C = (u16*)(ws + OFF_EB3);
  u16*   EBFC = (u16*)(ws + OFF_EBF);
  u16*   N1B0C= (u16*)(ws + OFF_N1B0);
  u16*   N1B1C= (u16*)(ws + OFF_N1B1);
  u16*   N2B0C= (u16*)(ws + OFF_N2B0);
  u16*   N2W1C= (u16*)(ws + OFF_N2W1);
  u16*   N2B1C= (u16*)(ws + OFF_N2B1);
  int*   OFFS = (int*)(ws + OFF_OFFS);
  int*   CUR  = (int*)(ws + OFF_CUR);
  float* UACC = (float*)(ws + OFF_UACC);
  u16*   W0T  = (u16*)(ws + OFF_W0T);
  u16*   W1T  = (u16*)(ws + OFF_W1T);
  u16*   W2T  = (u16*)(ws + OFF_W2T);
  u16*   W3T  = (u16*)(ws + OFF_W3T);
  u16*   WFT  = (u16*)(ws + OFF_WFT);
  u16*   N1W0T= (u16*)(ws + OFF_N1W0);
  u16*   N1W1T= (u16*)(ws + OFF_N1W1);
  u16*   N2W0T= (u16*)(ws + OFF_N2W0);
  u16*   UR   = (u16*)(ws + OFF_UR);
  int*   CNT  = (int*)(ws + OFF_CNT);
  float* AGG  = (float*)(ws + OFF_AGG);
  (void)in_sizes; (void)n_in; (void)out_size;

  // dynamic sizing: 2 ping-pong buffers of echunk x 1024 bf16 + perm ints
  int echunk = 16384;
  while (echunk > 2048 &&
         OFF_BUF0 + (size_t)echunk * 4096 + (size_t)NE * 4 > ws_size) echunk >>= 1;
  u16* P    = (u16*)(ws + OFF_BUF0);
  u16* Q    = (u16*)(ws + OFF_BUF0 + (size_t)echunk * 2048);
  int* EPRM = (int*)(ws + OFF_BUF0 + (size_t)echunk * 4096);
  const int nchunks = NE / echunk;
  const int nodch = echunk < NN ? echunk : NN;
  const int nodchn = NN / nodch;

  detect_dtype<<<1, 256, 0, stream>>>((const u16*)x_r, FLAG);

  CvtJob jb;
  const void* srcs[14] = {x_r, ea_r, u_r, b_dr, e_b0, e_b1, e_b2, e_b3,
                          e_bf, n1b0, n1b1, n2b0, n2w1, n2b1};
  void* dsts[14] = {XC, EAC, UC, BDRC, EB0C, EB1C, EB2C, EB3C,
                    EBFC, N1B0C, N1B1C, N2B0C, N2W1C, N2B1C};
  const int ns[14] = {147456, 131072, 65536, 256, 1024, 1024, 1024, 1024,
                      512, 512, 512, 512, 512, 1};
  int tot = 0;
  for (int j = 0; j < 14; j++) { jb.src[j] = srcs[j]; jb.dst[j] = dsts[j]; jb.n[j] = ns[j]; tot += ns[j]; }
  cvt_all<<<(tot + 255) / 256, 256, 0, stream>>>(jb, FLAG);

  transpose_pad<<<dim3(9, 32),  256, 0, stream>>>(e_w0, W0T,  275, 1024, 288, 0, FLAG);
  transpose_pad<<<dim3(32, 32), 256, 0, stream>>>(e_w1, W1T, 1024, 1024, 1024, 0, FLAG);
  transpose_pad<<<dim3(32, 32), 256, 0, stream>>>(e_w2, W2T, 1024, 1024, 1024, 0, FLAG);
  transpose_pad<<<dim3(32, 32), 256, 0, stream>>>(e_w3, W3T, 1024, 1024, 1024, 0, FLAG);
  transpose_pad<<<dim3(32, 16), 256, 0, stream>>>(e_wf, WFT, 1024, 512, 1024, 0, FLAG);
  transpose_pad<<<dim3(17, 16), 256, 0, stream>>>(n1w0, N1W0T, 521, 512, 544, 1, FLAG);
  transpose_pad<<<dim3(16, 16), 256, 0, stream>>>(n1w1, N1W1T, 512, 512, 512, 0, FLAG);
  transpose_pad<<<dim3(25, 16), 256, 0, stream>>>(n2w0, N2W0T, 777, 512, 800, 1, FLAG);

  (void)hipMemsetAsync(UACC, 0, 4096ull * 4, stream);
  (void)hipMemsetAsync(AGG, 0, 16384ull * 512 * 4, stream);
  (void)hipMemsetAsync(CNT, 0, 16384ull * 4, stream);

  dim_reduce2<<<dim3(NG, 8), 256, 0, stream>>>(UC, w_dr, UACC, FLAG);
  finish_ur<<<16, 256, 0, stream>>>(UACC, BDRC, UR);

  count_edges<<<NE / 256, 256, 0, stream>>>(row, CNT);
  prefix_offs<<<1, 256, 0, stream>>>(CNT, OFFS, CUR);
  build_perm<<<NE / 256, 256, 0, stream>>>(row, CUR, EPRM);

  for (int c = 0; c < nchunks; c++) {
    const int e0 = c * echunk;
    build_ein<<<echunk * 36 / 256, 256, 0, stream>>>(XC, EAC, UR, row, col, batch, EPRM, P, e0);
    gemm_bt<<<dim3(echunk / 128, 8), 256, 0, stream>>>(P, W0T, EB0C, Q, echunk, 1024, 288, 1024, 1);
    gemm_bt<<<dim3(echunk / 128, 8), 256, 0, stream>>>(Q, W1T, EB1C, P, echunk, 1024, 1024, 1024, 1);
    gemm_bt<<<dim3(echunk / 128, 8), 256, 0, stream>>>(P, W2T, EB2C, Q, echunk, 1024, 1024, 1024, 1);
    gemm_bt<<<dim3(echunk / 128, 8), 256, 0, stream>>>(Q, W3T, EB3C, P, echunk, 1024, 1024, 1024, 1);
    gemm_bt<<<dim3(echunk / 128, 4), 256, 0, stream>>>(P, WFT, EBFC, Q, echunk, 512, 1024, 544, 0);
    fill_nin1_tail<<<echunk * 4 / 256, 256, 0, stream>>>(XC, col, EPRM, Q, e0);
    gemm_bt<<<dim3(echunk / 128, 4), 256, 0, stream>>>(Q, N1W0T, N1B0C, P, echunk, 512, 544, 512, 1);
    gemm_bt<<<dim3(echunk / 128, 4), 256, 0, stream>>>(P, N1W1T, N1B1C, Q, echunk, 512, 512, 512, 1);
    seg_reduce<<<NN / 4, 256, 0, stream>>>(Q, OFFS, AGG, e0, echunk);
  }

  for (int c = 0; c < nodchn; c++) {
    const int n0 = c * nodch;
    build_nin2<<<nodch * 100 / 256, 256, 0, stream>>>(XC, AGG, CNT, UR, batch, P, n0);
    gemm_bt<<<dim3(nodch / 128, 4), 256, 0, stream>>>(P, N2W0T, N2B0C, Q, nodch, 512, 800, 512, 1);
    final_dot<<<nodch / 4, 256, 0, stream>>>(Q, N2W1C, N2B1C, d_out, n0, FLAG);
  }
}

// Round 14
// 2058.439 us; speedup vs baseline: 1.0954x; 1.0954x over previous
//
#include <hip/hip_runtime.h>
#include <type_traits>
#include <utility>
#include <cstdint>

typedef unsigned short u16;
typedef __attribute__((ext_vector_type(4))) float f32x4;
typedef __attribute__((ext_vector_type(8))) short s16x8;
typedef __attribute__((ext_vector_type(8))) __bf16 b16x8;

// ---- MFMA operand-type hedge: builtin takes either short8 or __bf16x8 ----
template <typename T, typename = void> struct MfmaTakes : std::false_type {};
template <typename T>
struct MfmaTakes<T, std::void_t<decltype(__builtin_amdgcn_mfma_f32_16x16x32_bf16(
    std::declval<T>(), std::declval<T>(), std::declval<f32x4>(), 0, 0, 0))>>
    : std::true_type {};
using abvec = std::conditional_t<MfmaTakes<s16x8>::value, s16x8, b16x8>;
static_assert(sizeof(abvec) == 16, "frag must be 4 VGPRs");

template <typename T>
__device__ __forceinline__ f32x4 mfma_bf16(T a, T b, f32x4 c) {
  return __builtin_amdgcn_mfma_f32_16x16x32_bf16(a, b, c, 0, 0, 0);
}

__device__ __forceinline__ float b2f(u16 v) {
  union { unsigned u; float f; } x; x.u = ((unsigned)v) << 16; return x.f;
}
__device__ __forceinline__ u16 f2b(float f) {
  union { float f; unsigned u; } x; x.f = f;
  unsigned r = x.u + 0x7fffu + ((x.u >> 16) & 1u);
  return (u16)(r >> 16);
}

__device__ __forceinline__ void gld16(const void* g, void* l) {
  auto gp = reinterpret_cast<const __attribute__((address_space(1))) unsigned int*>(
      reinterpret_cast<uintptr_t>(g));
  auto lp = reinterpret_cast<__attribute__((address_space(3))) unsigned int*>(
      reinterpret_cast<uintptr_t>(l));
  __builtin_amdgcn_global_load_lds(gp, lp, 16, 0, 0);
}

#define NN 16384
#define NE 131072
#define NG 16

// ---------------- dtype detect: bf16 vs f32 input buffers ----------------
__global__ void detect_dtype(const u16* __restrict__ x, int* __restrict__ flag) {
  __shared__ int cnt;
  if (threadIdx.x == 0) cnt = 0;
  __syncthreads();
  int local = 0;
#pragma unroll
  for (int i = 0; i < 8; i++) {
    u16 h = x[threadIdx.x * 8 + i];
    int e = (h >> 7) & 0xFF;
    if (h == 0 || (e >= 110 && e <= 134)) local++;
  }
  atomicAdd(&cnt, local);
  __syncthreads();
  if (threadIdx.x == 0) *flag = (cnt >= 1700) ? 1 : 0;
}

// ---------------- batched convert of tensors to bf16 ----------------
struct CvtJob {
  const void* src[14];
  void* dst[14];
  int n[14];
};

__global__ __launch_bounds__(256) void cvt_all(CvtJob jb, const int* __restrict__ flag) {
  const int idx = blockIdx.x * 256 + threadIdx.x;
  const int f = *flag;
  int off = 0;
#pragma unroll
  for (int j = 0; j < 14; j++) {
    const int nn = jb.n[j];
    if (idx < off + nn) {
      const int i = idx - off;
      u16 v = f ? ((const u16*)jb.src[j])[i]
                : f2b(((const float*)jb.src[j])[i]);
      ((u16*)jb.dst[j])[i] = v;
      return;
    }
    off += nn;
  }
}

// ---------------- GEMM: C[M,N](ldc) = act(A[M,K] @ Bt[N,K]^T + bias) ----------------
// True 2-stage pipelined K-loop: stage(t+1) issued AFTER the barrier, BEFORE
// compute(t) -> gld(t+1) in flight during compute(t); next barrier drains only
// the latency remainder. BK=32 ping-pong via arithmetic LDS offsets (no pointer
// arrays -> no addrspacecast static init). XOR k-slot swizzle + wave-private
// epilogue retained.
__global__ __launch_bounds__(256) void gemm_bt(
    const u16* __restrict__ A, const u16* __restrict__ Bt,
    const u16* __restrict__ bias, u16* __restrict__ C,
    int M, int N, int K, int ldc, int relu)
{
  __shared__ alignas(16) u16 smem[16384];  // 32KB: A0,A1,B0,B1 (4096 u16 each)
  const int tid = threadIdx.x;
  const int wave = tid >> 6, lane = tid & 63;
  const int m0 = blockIdx.x * 128, n0 = blockIdx.y * 128;

  const int srow = lane >> 2;              // 0..15
  const int kslot = lane & 3;              // 16B slot within row's 64B
  const int sswz = (srow >> 1) & 3;        // row-based XOR swizzle
  const u16* gA = A + (size_t)(m0 + wave * 32 + srow) * K + (kslot ^ sswz) * 8;
  const u16* gB = Bt + (size_t)(n0 + wave * 32 + srow) * K + (kslot ^ sswz) * 8;
  const int loff = (wave * 32 + srow) * 32 + kslot * 8;  // == wave*2048B + lane*16B

  const int wm = (wave >> 1) * 64;
  const int wn = (wave & 1) * 64;
  const int fr = lane & 15;
  const int fks = ((lane >> 4) ^ ((fr >> 1) & 3)) * 8;   // swizzled read slot

  f32x4 acc[4][4] = {};

  const int NT = K >> 5;                   // BK=32 tiles
  // prologue: stage tile 0 into set 0 (A at 0, B at 8192)
  gld16(gA, smem + loff); gld16(gA + 16 * (size_t)K, smem + loff + 512);
  gld16(gB, smem + 8192 + loff); gld16(gB + 16 * (size_t)K, smem + 8192 + loff + 512);

  for (int t = 0; t < NT; t++) {
    __syncthreads();                       // drains gld(t); other set is free
    if (t + 1 < NT) {
      const int o = (t + 1) * 32;
      const int soff = ((t + 1) & 1) << 12;        // 0 or 4096 u16
      u16* As = smem + soff;
      u16* Bs = smem + 8192 + soff;
      gld16(gA + o, As + loff); gld16(gA + 16 * (size_t)K + o, As + loff + 512);
      gld16(gB + o, Bs + loff); gld16(gB + 16 * (size_t)K + o, Bs + loff + 512);
    }
    const int coff = (t & 1) << 12;
    const u16* As = smem + coff;
    const u16* Bs = smem + 8192 + coff;
    abvec af[4], bf[4];
#pragma unroll
    for (int i = 0; i < 4; i++)
      af[i] = *(const abvec*)&As[(wm + i * 16 + fr) * 32 + fks];
#pragma unroll
    for (int i = 0; i < 4; i++)
      bf[i] = *(const abvec*)&Bs[(wn + i * 16 + fr) * 32 + fks];
#pragma unroll
    for (int mi = 0; mi < 4; mi++)
#pragma unroll
      for (int ni = 0; ni < 4; ni++)
        acc[mi][ni] = mfma_bf16(af[mi], bf[ni], acc[mi][ni]);
  }

  // ---- epilogue: wave-private LDS staging (one barrier, no inter-wave serial) ----
  const int crow0 = (lane >> 4) * 4;
  float bv[4];
#pragma unroll
  for (int ni = 0; ni < 4; ni++) bv[ni] = b2f(bias[n0 + wn + ni * 16 + fr]);

  __syncthreads();                         // all waves done reading As/Bs
  u16* W = smem + wave * 4096;             // private 64x64, col8 ^ (row&7) swizzle
#pragma unroll
  for (int mi = 0; mi < 4; mi++) {
#pragma unroll
    for (int ni = 0; ni < 4; ni++) {
      f32x4 v = acc[mi][ni];
      const int colx = ni * 16 + fr;
      const int cl = colx & 7, ch = colx >> 3;
#pragma unroll
      for (int r = 0; r < 4; r++) {
        const int rowx = mi * 16 + crow0 + r;
        float f = v[r] + bv[ni];
        if (relu) f = fmaxf(f, 0.0f);
        W[rowx * 64 + ((ch ^ (rowx & 7)) << 3) + cl] = f2b(f);
      }
    }
  }
  __asm__ volatile("s_waitcnt lgkmcnt(0)" ::: "memory");
#pragma unroll
  for (int p = 0; p < 8; p++) {
    const int rowx = p * 8 + (lane >> 3);
    const int pc = lane & 7;
    const int lc = pc ^ (rowx & 7);
    s16x8 val = *(const s16x8*)&W[rowx * 64 + pc * 8];
    *(s16x8*)&C[(size_t)(m0 + wm + rowx) * ldc + n0 + wn + lc * 8] = val;
  }
}

// -------- transpose + zero-pad + convert + optional K-permute --------
__global__ __launch_bounds__(256) void transpose_pad(
    const void* __restrict__ src, u16* __restrict__ dst, int K, int N, int Kp,
    int perm, const int* __restrict__ flag)
{
  __shared__ u16 tile[32][33];
  const int f = *flag;
  const u16* s16p = (const u16*)src;
  const float* sfp = (const float*)src;
  const int kb = blockIdx.x * 32, nb = blockIdx.y * 32;
  const int tx = threadIdx.x & 31, ty = threadIdx.x >> 5;
#pragma unroll
  for (int i = 0; i < 32; i += 8) {
    int k = kb + ty + i, n = nb + tx;
    u16 v = 0;
    if (k < K && n < N)
      v = f ? s16p[(size_t)k * N + n] : f2b(sfp[(size_t)k * N + n]);
    tile[ty + i][tx] = v;
  }
  __syncthreads();
#pragma unroll
  for (int i = 0; i < 32; i += 8) {
    int n = nb + ty + i, k = kb + tx;
    if (n < N && k < Kp) {
      int nk = perm ? (k < 9 ? 512 + k : (k < 521 ? k - 9 : k)) : k;
      dst[(size_t)n * Kp + nk] = tile[tx][ty + i];
    }
  }
}

// -------- dim_reduce K-split: grid (16 graphs, 8 k-tiles), partials into f32 --------
__global__ __launch_bounds__(256) void dim_reduce2(
    const u16* __restrict__ u, const void* __restrict__ w,
    float* __restrict__ uacc, const int* __restrict__ flag)
{
  const int g = blockIdx.x, kt = blockIdx.y, j = threadIdx.x;
  const int f = *flag;
  __shared__ u16 us[512];
  us[j] = u[g * 4096 + kt * 512 + j];
  us[256 + j] = u[g * 4096 + kt * 512 + 256 + j];
  __syncthreads();
  float acc = 0.0f;
  if (f) {
    const u16* wp = (const u16*)w + (size_t)(kt * 512) * 256 + j;
#pragma unroll 8
    for (int k = 0; k < 512; k++) acc += b2f(us[k]) * b2f(wp[(size_t)k * 256]);
  } else {
    const float* wp = (const float*)w + (size_t)(kt * 512) * 256 + j;
#pragma unroll 8
    for (int k = 0; k < 512; k++) acc += b2f(us[k]) * wp[(size_t)k * 256];
  }
  atomicAdd(&uacc[g * 256 + j], acc);
}

__global__ __launch_bounds__(256) void finish_ur(
    const float* __restrict__ uacc, const u16* __restrict__ bdr,
    u16* __restrict__ ur)
{
  const int i = blockIdx.x * 256 + threadIdx.x;  // 4096
  ur[i] = f2b(uacc[i] + b2f(bdr[i & 255]));
}

// -------- edge sort by row: count -> prefix -> perm --------
__global__ __launch_bounds__(256) void count_edges(
    const int* __restrict__ row, int* __restrict__ cnt)
{
  const int e = blockIdx.x * 256 + threadIdx.x;
  if (e < NE) atomicAdd(&cnt[row[e]], 1);
}

__global__ __launch_bounds__(256) void prefix_offs(
    const int* __restrict__ cnt, int* __restrict__ offs, int* __restrict__ cursor)
{
  __shared__ int part[256];
  __shared__ int base[256];
  const int t = threadIdx.x;
  int s = 0;
#pragma unroll
  for (int i = 0; i < 64; i++) s += cnt[t * 64 + i];
  part[t] = s;
  __syncthreads();
  if (t == 0) {
    int r = 0;
    for (int i = 0; i < 256; i++) { base[i] = r; r += part[i]; }
  }
  __syncthreads();
  int r = base[t];
#pragma unroll
  for (int i = 0; i < 64; i++) {
    const int n = t * 64 + i;
    offs[n] = r; cursor[n] = r; r += cnt[n];
  }
  if (t == 255) offs[16384] = r;   // == NE
}

__global__ __launch_bounds__(256) void build_perm(
    const int* __restrict__ row, int* __restrict__ cursor, int* __restrict__ eperm)
{
  const int e = blockIdx.x * 256 + threadIdx.x;
  const int pos = atomicAdd(&cursor[row[e]], 1);
  eperm[pos] = e;
}

// -------- edge input gather (sorted order) --------
__global__ __launch_bounds__(256) void build_ein(
    const u16* __restrict__ x, const u16* __restrict__ ea,
    const u16* __restrict__ ur, const int* __restrict__ row,
    const int* __restrict__ col, const int* __restrict__ batch,
    const int* __restrict__ eperm, u16* __restrict__ out, int e0)
{
  const int idx = blockIdx.x * 256 + threadIdx.x;   // echunk*36
  const int le = idx / 36, g = idx % 36;
  const int c0 = g * 8;
  const int e = eperm[e0 + le];
  const int r = row[e];
  alignas(16) u16 v[8];
  if (c0 >= 24 && c0 + 8 <= 275) {
    const u16* up = &ur[batch[r] * 256 + (c0 - 19)];
#pragma unroll
    for (int j = 0; j < 8; j++) v[j] = up[j];
  } else {
    const int cl = col[e];
    const int b = batch[r];
#pragma unroll
    for (int j = 0; j < 8; j++) {
      const int c = c0 + j;
      u16 t;
      if (c < 9)        t = x[r * 9 + c];
      else if (c < 18)  t = x[cl * 9 + (c - 9)];
      else if (c == 18) t = ea[e];
      else if (c < 275) t = ur[b * 256 + (c - 19)];
      else              t = 0;
      v[j] = t;
    }
  }
  *(s16x8*)&out[(size_t)le * 288 + c0] = *(const s16x8*)v;
}

// -------- fill nin1 cols 512..543 (sorted order) --------
__global__ __launch_bounds__(256) void fill_nin1_tail(
    const u16* __restrict__ x, const int* __restrict__ col,
    const int* __restrict__ eperm, u16* __restrict__ out, int e0)
{
  const int idx = blockIdx.x * 256 + threadIdx.x;   // echunk*4
  const int le = idx >> 2, j8 = idx & 3;
  const int c0 = 512 + j8 * 8;
  const int cl = col[eperm[e0 + le]];
  alignas(16) u16 v[8];
#pragma unroll
  for (int j = 0; j < 8; j++) {
    const int c = c0 + j;
    v[j] = (c < 521) ? x[cl * 9 + (c - 512)] : (u16)0;
  }
  *(s16x8*)&out[(size_t)le * 544 + c0] = *(const s16x8*)v;
}

// -------- segment reduce (sorted rows, no atomics; chunks stream-serialized) --------
__global__ __launch_bounds__(256) void seg_reduce(
    const u16* __restrict__ h, const int* __restrict__ offs,
    float* __restrict__ agg, int e0, int echunk)
{
  const int wave = threadIdx.x >> 6, lane = threadIdx.x & 63;
  const int n = blockIdx.x * 4 + wave;
  int lo = offs[n], hi = offs[n + 1];
  lo = lo > e0 ? lo : e0;
  const int e1 = e0 + echunk;
  hi = hi < e1 ? hi : e1;
  if (lo >= hi) return;
  const int c0 = lane * 8;
  float acc[8] = {};
  for (int i = lo; i < hi; i++) {
    s16x8 v = *(const s16x8*)&h[(size_t)(i - e0) * 512 + c0];
#pragma unroll
    for (int j = 0; j < 8; j++) acc[j] += b2f((u16)v[j]);
  }
  float* ap = &agg[(size_t)n * 512 + c0];
#pragma unroll
  for (int j = 0; j < 8; j++) ap[j] += acc[j];
}

// -------- nin2 build (permuted): [agg/cnt(512) | x(9) | ur(256) | pad(23)] --------
__global__ __launch_bounds__(256) void build_nin2(
    const u16* __restrict__ x, const float* __restrict__ agg,
    const int* __restrict__ cnt, const u16* __restrict__ ur,
    const int* __restrict__ batch, u16* __restrict__ out, int n0)
{
  const int idx = blockIdx.x * 256 + threadIdx.x;   // nodch*100
  const int le = idx / 100, g = idx % 100;
  const int c0 = g * 8;
  const int n = n0 + le;
  alignas(16) u16 v[8];
  if (c0 < 512) {
    const float den = fmaxf((float)cnt[n], 1.0f);
    const f32x4* ap = (const f32x4*)&agg[(size_t)n * 512 + c0];
    f32x4 a0 = ap[0], a1 = ap[1];
#pragma unroll
    for (int j = 0; j < 4; j++) { v[j] = f2b(a0[j] / den); v[4 + j] = f2b(a1[j] / den); }
  } else {
    const int b = batch[n];
#pragma unroll
    for (int j = 0; j < 8; j++) {
      const int c = c0 + j;
      u16 t;
      if (c < 521)      t = x[n * 9 + (c - 512)];
      else if (c < 777) t = ur[b * 256 + (c - 521)];
      else              t = 0;
      v[j] = t;
    }
  }
  *(s16x8*)&out[(size_t)le * 800 + c0] = *(const s16x8*)v;
}

// -------- final: out[n0+n] = h[n,:] . w + b --------
__global__ __launch_bounds__(256) void final_dot(
    const u16* __restrict__ h, const u16* __restrict__ w,
    const u16* __restrict__ b, void* __restrict__ out, int n0,
    const int* __restrict__ flag)
{
  const int wave = threadIdx.x >> 6, lane = threadIdx.x & 63;
  const int n = blockIdx.x * 4 + wave;
  const u16* hp = h + (size_t)n * 512 + lane * 8;
  const u16* wp = w + lane * 8;
  float s = 0.0f;
#pragma unroll
  for (int i = 0; i < 8; i++) s += b2f(hp[i]) * b2f(wp[i]);
#pragma unroll
  for (int off = 32; off > 0; off >>= 1) s += __shfl_down(s, off, 64);
  if (lane == 0) {
    float r = s + b2f(b[0]);
    if (*flag) ((u16*)out)[n0 + n] = f2b(r);
    else       ((float*)out)[n0 + n] = r;
  }
}

// ---------------- workspace layout (static part) ----------------
constexpr size_t OFF_FLAG = 0;
constexpr size_t OFF_XC   = 64;
constexpr size_t OFF_EAC  = OFF_XC   + 147456ull * 2;
constexpr size_t OFF_UC   = OFF_EAC  + 131072ull * 2;
constexpr size_t OFF_BDR  = OFF_UC   + 65536ull * 2;
constexpr size_t OFF_EB0  = OFF_BDR  + 256ull * 2;
constexpr size_t OFF_EB1  = OFF_EB0  + 1024ull * 2;
constexpr size_t OFF_EB2  = OFF_EB1  + 1024ull * 2;
constexpr size_t OFF_EB3  = OFF_EB2  + 1024ull * 2;
constexpr size_t OFF_EBF  = OFF_EB3  + 1024ull * 2;
constexpr size_t OFF_N1B0 = OFF_EBF  + 512ull * 2;
constexpr size_t OFF_N1B1 = OFF_N1B0 + 512ull * 2;
constexpr size_t OFF_N2B0 = OFF_N1B1 + 512ull * 2;
constexpr size_t OFF_N2W1 = OFF_N2B0 + 512ull * 2;
constexpr size_t OFF_N2B1 = OFF_N2W1 + 512ull * 2;
constexpr size_t OFF_OFFS = (OFF_N2B1 + 64 + 63) & ~63ull;     // 16385 int
constexpr size_t OFF_CUR  = OFF_OFFS + 16388ull * 4;           // 16384 int
constexpr size_t OFF_UACC = OFF_CUR  + 16384ull * 4;           // 4096 f32
static_assert(OFF_UACC + 4096 * 4 < (1ull << 20), "params+small fit in 1MB");

constexpr size_t OFF_W0T  = 1ull << 20;
constexpr size_t OFF_W1T  = OFF_W0T  + 1024ull * 288 * 2;
constexpr size_t OFF_W2T  = OFF_W1T  + 1024ull * 1024 * 2;
constexpr size_t OFF_W3T  = OFF_W2T  + 1024ull * 1024 * 2;
constexpr size_t OFF_WFT  = OFF_W3T  + 1024ull * 1024 * 2;
constexpr size_t OFF_N1W0 = OFF_WFT  + 512ull * 1024 * 2;
constexpr size_t OFF_N1W1 = OFF_N1W0 + 512ull * 544 * 2;
constexpr size_t OFF_N2W0 = OFF_N1W1 + 512ull * 512 * 2;
constexpr size_t OFF_UR   = OFF_N2W0 + 512ull * 800 * 2;
constexpr size_t OFF_CNT  = OFF_UR   + 16ull * 256 * 2;
constexpr size_t OFF_AGG  = OFF_CNT  + 16384ull * 4;
constexpr size_t OFF_BUF0 = OFF_AGG  + 16384ull * 512 * 4;   // dynamic from here (~42.5 MB)

extern "C" void kernel_launch(void* const* d_in, const int* in_sizes, int n_in,
                              void* d_out, int out_size, void* d_ws, size_t ws_size,
                              hipStream_t stream) {
  const void* x_r  = d_in[0];
  const void* ea_r = d_in[1];
  const void* u_r  = d_in[2];
  const int*  ei    = (const int*)d_in[3];
  const int*  batch = (const int*)d_in[4];
  const void* w_dr = d_in[5];
  const void* b_dr = d_in[6];
  const void* e_w0 = d_in[7];  const void* e_b0 = d_in[8];
  const void* e_w1 = d_in[9];  const void* e_b1 = d_in[10];
  const void* e_w2 = d_in[11]; const void* e_b2 = d_in[12];
  const void* e_w3 = d_in[13]; const void* e_b3 = d_in[14];
  const void* e_wf = d_in[15]; const void* e_bf = d_in[16];
  const void* n1w0 = d_in[17]; const void* n1b0 = d_in[18];
  const void* n1w1 = d_in[19]; const void* n1b1 = d_in[20];
  const void* n2w0 = d_in[21]; const void* n2b0 = d_in[22];
  const void* n2w1 = d_in[23]; const void* n2b1 = d_in[24];

  const int* row = ei;
  const int* col = ei + NE;

  char* ws = (char*)d_ws;
  int*   FLAG = (int*)(ws + OFF_FLAG);
  u16*   XC   = (u16*)(ws + OFF_XC);
  u16*   EAC  = (u16*)(ws + OFF_EAC);
  u16*   UC   = (u16*)(ws + OFF_UC);
  u16*   BDRC = (u16*)(ws + OFF_BDR);
  u16*   EB0C = (u16*)(ws + OFF_EB0);
  u16*   EB1C = (u16*)(ws + OFF_EB1);
  u16*   EB2C = (u16*)(ws + OFF_EB2);
  u16*   EB3C = (u16*)(ws + OFF_EB3);
  u16*   EBFC = (u16*)(ws + OFF_EBF);
  u16*   N1B0C= (u16*)(ws + OFF_N1B0);
  u16*   N1B1C= (u16*)(ws + OFF_N1B1);
  u16*   N2B0C= (u16*)(ws + OFF_N2B0);
  u16*   N2W1C= (u16*)(ws + OFF_N2W1);
  u16*   N2B1C= (u16*)(ws + OFF_N2B1);
  int*   OFFS = (int*)(ws + OFF_OFFS);
  int*   CUR  = (int*)(ws + OFF_CUR);
  float* UACC = (float*)(ws + OFF_UACC);
  u16*   W0T  = (u16*)(ws + OFF_W0T);
  u16*   W1T  = (u16*)(ws + OFF_W1T);
  u16*   W2T  = (u16*)(ws + OFF_W2T);
  u16*   W3T  = (u16*)(ws + OFF_W3T);
  u16*   WFT  = (u16*)(ws + OFF_WFT);
  u16*   N1W0T= (u16*)(ws + OFF_N1W0);
  u16*   N1W1T= (u16*)(ws + OFF_N1W1);
  u16*   N2W0T= (u16*)(ws + OFF_N2W0);
  u16*   UR   = (u16*)(ws + OFF_UR);
  int*   CNT  = (int*)(ws + OFF_CNT);
  float* AGG  = (float*)(ws + OFF_AGG);
  (void)in_sizes; (void)n_in; (void)out_size;

  // dynamic sizing: 2 ping-pong buffers of echunk x 1024 bf16 + perm ints
  int echunk = 16384;
  while (echunk > 2048 &&
         OFF_BUF0 + (size_t)echunk * 4096 + (size_t)NE * 4 > ws_size) echunk >>= 1;
  u16* P    = (u16*)(ws + OFF_BUF0);
  u16* Q    = (u16*)(ws + OFF_BUF0 + (size_t)echunk * 2048);
  int* EPRM = (int*)(ws + OFF_BUF0 + (size_t)echunk * 4096);
  const int nchunks = NE / echunk;
  const int nodch = echunk < NN ? echunk : NN;
  const int nodchn = NN / nodch;

  detect_dtype<<<1, 256, 0, stream>>>((const u16*)x_r, FLAG);

  CvtJob jb;
  const void* srcs[14] = {x_r, ea_r, u_r, b_dr, e_b0, e_b1, e_b2, e_b3,
                          e_bf, n1b0, n1b1, n2b0, n2w1, n2b1};
  void* dsts[14] = {XC, EAC, UC, BDRC, EB0C, EB1C, EB2C, EB3C,
                    EBFC, N1B0C, N1B1C, N2B0C, N2W1C, N2B1C};
  const int ns[14] = {147456, 131072, 65536, 256, 1024, 1024, 1024, 1024,
                      512, 512, 512, 512, 512, 1};
  int tot = 0;
  for (int j = 0; j < 14; j++) { jb.src[j] = srcs[j]; jb.dst[j] = dsts[j]; jb.n[j] = ns[j]; tot += ns[j]; }
  cvt_all<<<(tot + 255) / 256, 256, 0, stream>>>(jb, FLAG);

  transpose_pad<<<dim3(9, 32),  256, 0, stream>>>(e_w0, W0T,  275, 1024, 288, 0, FLAG);
  transpose_pad<<<dim3(32, 32), 256, 0, stream>>>(e_w1, W1T, 1024, 1024, 1024, 0, FLAG);
  transpose_pad<<<dim3(32, 32), 256, 0, stream>>>(e_w2, W2T, 1024, 1024, 1024, 0, FLAG);
  transpose_pad<<<dim3(32, 32), 256, 0, stream>>>(e_w3, W3T, 1024, 1024, 1024, 0, FLAG);
  transpose_pad<<<dim3(32, 16), 256, 0, stream>>>(e_wf, WFT, 1024, 512, 1024, 0, FLAG);
  transpose_pad<<<dim3(17, 16), 256, 0, stream>>>(n1w0, N1W0T, 521, 512, 544, 1, FLAG);
  transpose_pad<<<dim3(16, 16), 256, 0, stream>>>(n1w1, N1W1T, 512, 512, 512, 0, FLAG);
  transpose_pad<<<dim3(25, 16), 256, 0, stream>>>(n2w0, N2W0T, 777, 512, 800, 1, FLAG);

  (void)hipMemsetAsync(UACC, 0, 4096ull * 4, stream);
  (void)hipMemsetAsync(AGG, 0, 16384ull * 512 * 4, stream);
  (void)hipMemsetAsync(CNT, 0, 16384ull * 4, stream);

  dim_reduce2<<<dim3(NG, 8), 256, 0, stream>>>(UC, w_dr, UACC, FLAG);
  finish_ur<<<16, 256, 0, stream>>>(UACC, BDRC, UR);

  count_edges<<<NE / 256, 256, 0, stream>>>(row, CNT);
  prefix_offs<<<1, 256, 0, stream>>>(CNT, OFFS, CUR);
  build_perm<<<NE / 256, 256, 0, stream>>>(row, CUR, EPRM);

  for (int c = 0; c < nchunks; c++) {
    const int e0 = c * echunk;
    build_ein<<<echunk * 36 / 256, 256, 0, stream>>>(XC, EAC, UR, row, col, batch, EPRM, P, e0);
    gemm_bt<<<dim3(echunk / 128, 8), 256, 0, stream>>>(P, W0T, EB0C, Q, echunk, 1024, 288, 1024, 1);
    gemm_bt<<<dim3(echunk / 128, 8), 256, 0, stream>>>(Q, W1T, EB1C, P, echunk, 1024, 1024, 1024, 1);
    gemm_bt<<<dim3(echunk / 128, 8), 256, 0, stream>>>(P, W2T, EB2C, Q, echunk, 1024, 1024, 1024, 1);
    gemm_bt<<<dim3(echunk / 128, 8), 256, 0, stream>>>(Q, W3T, EB3C, P, echunk, 1024, 1024, 1024, 1);
    gemm_bt<<<dim3(echunk / 128, 4), 256, 0, stream>>>(P, WFT, EBFC, Q, echunk, 512, 1024, 544, 0);
    fill_nin1_tail<<<echunk * 4 / 256, 256, 0, stream>>>(XC, col, EPRM, Q, e0);
    gemm_bt<<<dim3(echunk / 128, 4), 256, 0, stream>>>(Q, N1W0T, N1B0C, P, echunk, 512, 544, 512, 1);
    gemm_bt<<<dim3(echunk / 128, 4), 256, 0, stream>>>(P, N1W1T, N1B1C, Q, echunk, 512, 512, 512, 1);
    seg_reduce<<<NN / 4, 256, 0, stream>>>(Q, OFFS, AGG, e0, echunk);
  }

  for (int c = 0; c < nodchn; c++) {
    const int n0 = c * nodch;
    build_nin2<<<nodch * 100 / 256, 256, 0, stream>>>(XC, AGG, CNT, UR, batch, P, n0);
    gemm_bt<<<dim3(nodch / 128, 4), 256, 0, stream>>>(P, N2W0T, N2B0C, Q, nodch, 512, 800, 512, 1);
    final_dot<<<nodch / 4, 256, 0, stream>>>(Q, N2W1C, N2B1C, d_out, n0, FLAG);
  }
}